// Round 2
// baseline (1491.772 us; speedup 1.0000x reference)
//
#include <hip/hip_runtime.h>
#include <hip/hip_bf16.h>

// MambaTower: B=1, L=2048, DM=256, E=512, N=16, R=16, K=4, NL=4, CA at layers 1,3
// All device tensors fp32 (reference is jnp.float32; npz sizes confirm fp32 on device).

constexpr int L_ = 2048, DM_ = 256, E_ = 512;

__device__ __forceinline__ float siluf(float x) { return x / (1.f + __expf(-x)); }

// ---------------- rmsnorm (row=256) ----------------
__global__ __launch_bounds__(256) void rmsnorm_k(const float* __restrict__ X,
                                                 const float* __restrict__ w,
                                                 float* __restrict__ Hout) {
  int lane = threadIdx.x & 63, wv = threadIdx.x >> 6;
  int row = blockIdx.x * 4 + wv;
  const float4 xv = *(const float4*)(X + (size_t)row * DM_ + lane * 4);
  float ss = xv.x * xv.x + xv.y * xv.y + xv.z * xv.z + xv.w * xv.w;
  #pragma unroll
  for (int off = 1; off < 64; off <<= 1) ss += __shfl_xor(ss, off);
  float sc = rsqrtf(ss * (1.f / DM_) + 1e-6f);
  const float4 wv4 = *(const float4*)(w + lane * 4);
  float4 o;
  o.x = xv.x * sc * wv4.x;
  o.y = xv.y * sc * wv4.y;
  o.z = xv.z * sc * wv4.z;
  o.w = xv.w * sc * wv4.w;
  *(float4*)(Hout + (size_t)row * DM_ + lane * 4) = o;
}

// ---------------- generic GEMM: C[MxN] (+)= act(A[MxK] * B[KxN] + bias) ----------------
// all fp32. ACT: 0=none 1=softplus. ADD: accumulate into C.
template<int ACT, int ADD, int BIAS>
__global__ __launch_bounds__(256) void gemm_k(
    const float* __restrict__ A, int lda,
    const float* __restrict__ B, int ldb,
    const float* __restrict__ bias,
    float* __restrict__ C, int ldc,
    int M, int N, int Kd) {
  __shared__ float As[32 * 65];  // transposed [k][m], pad 65
  __shared__ float Bs[32 * 68];  // [k][n], pad 68 (float4-aligned)
  const int tid = threadIdx.x;
  const int m0 = blockIdx.y * 64, n0 = blockIdx.x * 64;
  const int tm = tid >> 4, tn = tid & 15;
  float acc[4][4] = {{0.f}};
  for (int k0 = 0; k0 < Kd; k0 += 32) {
    __syncthreads();
    // load A tile (64 rows x 32 k), zero-padded
    #pragma unroll
    for (int it = 0; it < 2; ++it) {
      int m = (tid >> 3) + it * 32;
      int ks = (tid & 7) * 4;
      float v0 = 0.f, v1 = 0.f, v2 = 0.f, v3 = 0.f;
      int gm = m0 + m;
      if (gm < M) {
        const float* ap = A + (size_t)gm * lda + k0 + ks;
        int rem = Kd - (k0 + ks);
        if (rem >= 4) { v0 = ap[0]; v1 = ap[1]; v2 = ap[2]; v3 = ap[3]; }
        else { if (rem > 0) v0 = ap[0]; if (rem > 1) v1 = ap[1]; if (rem > 2) v2 = ap[2]; }
      }
      As[(ks + 0) * 65 + m] = v0;
      As[(ks + 1) * 65 + m] = v1;
      As[(ks + 2) * 65 + m] = v2;
      As[(ks + 3) * 65 + m] = v3;
    }
    // load B tile (32 k x 64 n), zero-padded
    {
      int k = tid >> 3;
      int nn = (tid & 7) * 8;
      int gk = k0 + k;
      if (gk < Kd && (n0 + nn + 8) <= N) {
        const float* p = B + (size_t)gk * ldb + n0 + nn;
        *(float4*)&Bs[k * 68 + nn]     = *(const float4*)p;
        *(float4*)&Bs[k * 68 + nn + 4] = *(const float4*)(p + 4);
      } else {
        #pragma unroll
        for (int j = 0; j < 8; ++j) {
          int gn = n0 + nn + j;
          Bs[k * 68 + nn + j] = (gk < Kd && gn < N) ? B[(size_t)gk * ldb + gn] : 0.f;
        }
      }
    }
    __syncthreads();
    #pragma unroll
    for (int kk = 0; kk < 32; ++kk) {
      float4 b = *(const float4*)&Bs[kk * 68 + tn * 4];
      #pragma unroll
      for (int r = 0; r < 4; ++r) {
        float a = As[kk * 65 + tm * 4 + r];
        acc[r][0] = fmaf(a, b.x, acc[r][0]);
        acc[r][1] = fmaf(a, b.y, acc[r][1]);
        acc[r][2] = fmaf(a, b.z, acc[r][2]);
        acc[r][3] = fmaf(a, b.w, acc[r][3]);
      }
    }
  }
  #pragma unroll
  for (int r = 0; r < 4; ++r) {
    int gm = m0 + tm * 4 + r;
    if (gm >= M) continue;
    #pragma unroll
    for (int c = 0; c < 4; ++c) {
      int gn = n0 + tn * 4 + c;
      if (gn >= N) continue;
      float v = acc[r][c];
      if (BIAS) v += bias[gn];
      if (ACT == 1) v = (v > 20.f) ? v : log1pf(__expf(v));
      float* cp = C + (size_t)gm * ldc + gn;
      if (ADD) *cp += v; else *cp = v;
    }
  }
}

// ---------------- depthwise causal conv (both directions) + silu ----------------
__global__ void conv_k(const float* __restrict__ XZ, const float* __restrict__ cw,
                       const float* __restrict__ cb, float* __restrict__ UC) {
  int idx = blockIdx.x * 256 + threadIdx.x;
  if (idx >= L_ * E_) return;
  int e = idx & (E_ - 1);
  int l = idx >> 9;
  float w0 = cw[0 * E_ + e], w1 = cw[1 * E_ + e];
  float w2 = cw[2 * E_ + e], w3 = cw[3 * E_ + e];
  float b = cb[e];
  float af = b, ab = b;
  #pragma unroll
  for (int k = 0; k < 4; ++k) {
    int j = l - 3 + k;
    if (j >= 0) {
      float wk = (k == 0) ? w0 : (k == 1) ? w1 : (k == 2) ? w2 : w3;
      af += wk * XZ[(size_t)j * 1024 + e];
      ab += wk * XZ[(size_t)(L_ - 1 - j) * 1024 + e];
    }
  }
  UC[idx] = siluf(af);
  UC[L_ * E_ + idx] = siluf(ab);
}

// ---------------- chunked selective scan ----------------
__global__ __launch_bounds__(256) void scan1_k(
    const float* __restrict__ DTb, const float* __restrict__ UCb, const float* __restrict__ PRb,
    const float* __restrict__ alog, float* __restrict__ SP, float* __restrict__ SH) {
  int b = blockIdx.x;  // 2*8*32
  int eg = b & 31, chunk = (b >> 5) & 7, dir = b >> 8;
  int tid = threadIdx.x;
  int n = tid & 15, e = eg * 16 + (tid >> 4);
  const float* dt = DTb + (size_t)dir * L_ * E_;
  const float* uc = UCb + (size_t)dir * L_ * E_;
  const float* pr = PRb + (size_t)dir * L_ * 48;
  float A = -__expf(alog[e * 16 + n]);
  float P = 1.f, h = 0.f;
  int l0 = chunk * 256;
  #pragma unroll 4
  for (int l = l0; l < l0 + 256; ++l) {
    float d = dt[(size_t)l * E_ + e];
    float u = uc[(size_t)l * E_ + e];
    float Bv = pr[(size_t)l * 48 + 16 + n];
    float a = __expf(d * A);
    P *= a;
    h = fmaf(a, h, d * Bv * u);
  }
  int idx = ((dir * 8 + chunk) * E_ + e) * 16 + n;
  SP[idx] = P;
  SH[idx] = h;
}

__global__ void scan2_k(const float* __restrict__ SP, const float* __restrict__ SH,
                        float* __restrict__ CIN) {
  int idx = blockIdx.x * 256 + threadIdx.x;  // 2*8192
  if (idx >= 2 * E_ * 16) return;
  int dir = idx >> 13, en = idx & 8191;
  float c = 0.f;
  #pragma unroll
  for (int j = 0; j < 8; ++j) {
    int s = (dir * 8 + j) * 8192 + en;
    CIN[s] = c;
    c = SP[s] * c + SH[s];
  }
}

__global__ __launch_bounds__(256) void scan3_k(
    const float* __restrict__ DTb, const float* __restrict__ UCb, const float* __restrict__ PRb,
    const float* __restrict__ alog, const float* __restrict__ dp,
    const float* __restrict__ CIN, float* __restrict__ Y2) {
  int b = blockIdx.x;
  int eg = b & 31, chunk = (b >> 5) & 7, dir = b >> 8;
  int tid = threadIdx.x;
  int n = tid & 15, e = eg * 16 + (tid >> 4);
  const float* dt = DTb + (size_t)dir * L_ * E_;
  const float* uc = UCb + (size_t)dir * L_ * E_;
  const float* pr = PRb + (size_t)dir * L_ * 48;
  float* Y = Y2 + (size_t)dir * L_ * E_;
  float A = -__expf(alog[e * 16 + n]);
  float D = dp[e];
  float h = CIN[((dir * 8 + chunk) * E_ + e) * 16 + n];
  int l0 = chunk * 256;
  #pragma unroll 2
  for (int l = l0; l < l0 + 256; ++l) {
    float d = dt[(size_t)l * E_ + e];
    float u = uc[(size_t)l * E_ + e];
    float Bv = pr[(size_t)l * 48 + 16 + n];
    float Cv = pr[(size_t)l * 48 + 32 + n];
    float a = __expf(d * A);
    h = fmaf(a, h, d * Bv * u);
    float contrib = h * Cv;
    contrib += __shfl_xor(contrib, 1);
    contrib += __shfl_xor(contrib, 2);
    contrib += __shfl_xor(contrib, 4);
    contrib += __shfl_xor(contrib, 8);
    if (n == 0) Y[(size_t)l * E_ + e] = contrib + u * D;
  }
}

// ---------------- combine fwd+bwd, gate by silu(z) ----------------
__global__ void combine_k(const float* __restrict__ Y2, const float* __restrict__ XZ,
                          float* __restrict__ YG) {
  int idx = blockIdx.x * 256 + threadIdx.x;
  if (idx >= L_ * E_) return;
  int e = idx & (E_ - 1);
  int l = idx >> 9;
  float y = Y2[idx] + Y2[L_ * E_ + (size_t)(L_ - 1 - l) * E_ + e];
  float z = XZ[(size_t)l * 1024 + 512 + e];
  YG[idx] = y * siluf(z);
}

// ---------------- cross-attention core ----------------
// per (l,h): G[c]=sum_d kw[c,h*64+d]*Q[l,h,d]; logits[t]=sum_c tf[l,t,c]*G[c] (k_b softmax-invariant)
// w=softmax(logits/8); m[c]=sum_t w[t]*tf[l,t,c]; out[d]=sum_c m[c]*vw[c,h*64+d]+vb
__global__ __launch_bounds__(256) void attn_k(
    const float* __restrict__ Q, const float* __restrict__ te,
    const float* __restrict__ kw, const float* __restrict__ vw, const float* __restrict__ vb,
    float* __restrict__ AO) {
  int lane = threadIdx.x & 63, h = threadIdx.x >> 6;
  int l0 = blockIdx.x * 16;
  const float* kp0 = kw + (size_t)lane * DM_ + h * 64;
  const float* vp0 = vw + h * 64 + lane;
  float vbv = vb[h * 64 + lane];
  for (int p = 0; p < 16; ++p) {
    int l = l0 + p;
    float q = Q[(size_t)l * DM_ + h * 64 + lane];
    float g = 0.f;
    #pragma unroll
    for (int d0 = 0; d0 < 64; d0 += 4) {
      float4 r = *(const float4*)(kp0 + d0);
      g = fmaf(r.x, __shfl(q, d0 + 0), g);
      g = fmaf(r.y, __shfl(q, d0 + 1), g);
      g = fmaf(r.z, __shfl(q, d0 + 2), g);
      g = fmaf(r.w, __shfl(q, d0 + 3), g);
    }
    float tfv[8], pv[8];
    #pragma unroll
    for (int t = 0; t < 8; ++t) {
      tfv[t] = te[(size_t)t * L_ * 64 + (size_t)l * 64 + lane];
      pv[t] = tfv[t] * g;
    }
    #pragma unroll
    for (int t = 0; t < 8; ++t) {
      #pragma unroll
      for (int off = 1; off < 64; off <<= 1) pv[t] += __shfl_xor(pv[t], off);
    }
    float mx = pv[0];
    #pragma unroll
    for (int t = 1; t < 8; ++t) mx = fmaxf(mx, pv[t]);
    float s = 0.f;
    #pragma unroll
    for (int t = 0; t < 8; ++t) { pv[t] = __expf((pv[t] - mx) * 0.125f); s += pv[t]; }
    float inv = 1.f / s;
    float m = 0.f;
    #pragma unroll
    for (int t = 0; t < 8; ++t) m = fmaf(pv[t] * inv, tfv[t], m);
    float o = vbv;
    #pragma unroll 8
    for (int c = 0; c < 64; ++c)
      o = fmaf(__shfl(m, c), vp0[(size_t)c * DM_], o);
    AO[(size_t)l * DM_ + h * 64 + lane] = o;
  }
}

extern "C" void kernel_launch(void* const* d_in, const int* in_sizes, int n_in,
                              void* d_out, int out_size, void* d_ws, size_t ws_size,
                              hipStream_t stream) {
  (void)in_sizes; (void)n_in; (void)out_size; (void)ws_size;
  const float* x_in = (const float*)d_in[0];
  const float* te   = (const float*)d_in[1];
  const float* mnw  = (const float*)d_in[2];
  const float* ipw  = (const float*)d_in[3];
  const float* cw   = (const float*)d_in[4];
  const float* cb   = (const float*)d_in[5];
  const float* xpw  = (const float*)d_in[6];
  const float* dpw  = (const float*)d_in[7];
  const float* dpb  = (const float*)d_in[8];
  const float* alog = (const float*)d_in[9];
  const float* dprm = (const float*)d_in[10];
  const float* opw  = (const float*)d_in[11];
  const float* cnw  = (const float*)d_in[12];
  const float* qw   = (const float*)d_in[13];
  const float* qb   = (const float*)d_in[14];
  const float* kw   = (const float*)d_in[15];
  // d_in[16] = k_b: constant over tracks -> softmax-invariant, unused
  const float* vw   = (const float*)d_in[17];
  const float* vb   = (const float*)d_in[18];
  const float* ow   = (const float*)d_in[19];
  const float* ob   = (const float*)d_in[20];

  float* ws = (float*)d_ws;
  // workspace layout (floats); Hb/YG/Qb/AO alias dead regions
  float* X   = ws + 0;         // 524288
  float* XZ  = ws + 524288;    // 2097152
  float* UC  = ws + 2621440;   // 2097152 (dir0, dir1)
  float* DTm = ws + 4718592;   // 2097152
  float* PR  = ws + 6815744;   // 196608
  float* Y2  = ws + 7012352;   // 2097152
  float* SP  = ws + 9109504;   // 131072
  float* SH  = ws + 9240576;   // 131072
  float* CIN = ws + 9371648;   // 131072  (end 9502720 floats = 38 MB)
  float* Hb  = UC + 1048576;   // alias UC dir1 (dead when used)
  float* YG  = UC;             // alias UC dir0 (dead after scan3)
  float* Qb  = DTm;            // alias DTm (dead in CA)
  float* AO  = DTm + 524288;

  hipMemcpyAsync(X, x_in, (size_t)L_ * DM_ * sizeof(float),
                 hipMemcpyDeviceToDevice, stream);

  for (int i = 0; i < 4; ++i) {
    rmsnorm_k<<<512, 256, 0, stream>>>(X, mnw + i * 256, Hb);
    gemm_k<0,0,0><<<dim3(16, 32), 256, 0, stream>>>(
        Hb, 256, ipw + (size_t)i * 256 * 1024, 1024, nullptr, XZ, 1024, L_, 1024, 256);
    conv_k<<<4096, 256, 0, stream>>>(XZ, cw + i * 4 * 512, cb + i * 512, UC);
    for (int dir = 0; dir < 2; ++dir) {
      gemm_k<0,0,0><<<dim3(1, 32), 256, 0, stream>>>(
          UC + (size_t)dir * 1048576, 512, xpw + (size_t)i * 512 * 48, 48, nullptr,
          PR + (size_t)dir * 98304, 48, L_, 48, 512);
      gemm_k<1,0,1><<<dim3(8, 32), 256, 0, stream>>>(
          PR + (size_t)dir * 98304, 48, dpw + (size_t)i * 16 * 512, 512, dpb + i * 512,
          DTm + (size_t)dir * 1048576, 512, L_, 512, 16);
    }
    scan1_k<<<512, 256, 0, stream>>>(DTm, UC, PR, alog + (size_t)i * 512 * 16, SP, SH);
    scan2_k<<<64, 256, 0, stream>>>(SP, SH, CIN);
    scan3_k<<<512, 256, 0, stream>>>(DTm, UC, PR, alog + (size_t)i * 512 * 16,
                                     dprm + i * 512, CIN, Y2);
    combine_k<<<4096, 256, 0, stream>>>(Y2, XZ, YG);
    gemm_k<0,1,0><<<dim3(4, 32), 256, 0, stream>>>(
        YG, 512, opw + (size_t)i * 512 * 256, 256, nullptr, X, 256, L_, 256, 512);

    if (i == 1 || i == 3) {
      int j = (i == 1) ? 0 : 1;
      rmsnorm_k<<<512, 256, 0, stream>>>(X, cnw + j * 256, Hb);
      gemm_k<0,0,1><<<dim3(4, 32), 256, 0, stream>>>(
          Hb, 256, qw + (size_t)j * 256 * 256, 256, qb + j * 256, Qb, 256, L_, 256, 256);
      attn_k<<<128, 256, 0, stream>>>(Qb, te, kw + (size_t)j * 64 * 256,
                                      vw + (size_t)j * 64 * 256, vb + j * 256, AO);
      gemm_k<0,1,1><<<dim3(4, 32), 256, 0, stream>>>(
          AO, 256, ow + (size_t)j * 256 * 256, 256, ob + j * 256, X, 256, L_, 256, 256);
    }
  }

  hipMemcpyAsync(d_out, X, (size_t)L_ * DM_ * sizeof(float),
                 hipMemcpyDeviceToDevice, stream);
}

// Round 3
// 916.531 us; speedup vs baseline: 1.6276x; 1.6276x over previous
//
#include <hip/hip_runtime.h>
#include <hip/hip_bf16.h>

// MambaTower: B=1, L=2048, DM=256, E=512, N=16, R=16, K=4, NL=4, CA at layers 1,3
// All device tensors fp32. Scans: 32 chunks x 64 steps, LDS-staged tiles.

constexpr int L_ = 2048, DM_ = 256, E_ = 512;
constexpr int CH = 32, CL = 64;  // chunks, chunk length (CH*CL == L_)

__device__ __forceinline__ float siluf(float x) { return x / (1.f + __expf(-x)); }

// ---------------- rmsnorm (row=256) ----------------
__global__ __launch_bounds__(256) void rmsnorm_k(const float* __restrict__ X,
                                                 const float* __restrict__ w,
                                                 float* __restrict__ Hout) {
  int lane = threadIdx.x & 63, wv = threadIdx.x >> 6;
  int row = blockIdx.x * 4 + wv;
  const float4 xv = *(const float4*)(X + (size_t)row * DM_ + lane * 4);
  float ss = xv.x * xv.x + xv.y * xv.y + xv.z * xv.z + xv.w * xv.w;
  #pragma unroll
  for (int off = 1; off < 64; off <<= 1) ss += __shfl_xor(ss, off);
  float sc = rsqrtf(ss * (1.f / DM_) + 1e-6f);
  const float4 wv4 = *(const float4*)(w + lane * 4);
  float4 o;
  o.x = xv.x * sc * wv4.x;
  o.y = xv.y * sc * wv4.y;
  o.z = xv.z * sc * wv4.z;
  o.w = xv.w * sc * wv4.w;
  *(float4*)(Hout + (size_t)row * DM_ + lane * 4) = o;
}

// ---------------- generic GEMM: C[MxN] (+)= act(A[MxK] * B[KxN] + bias) ----------------
// fp32. ACT: 0=none 1=softplus. ADD: accumulate. Batched over blockIdx.z via saz/scz.
template<int ACT, int ADD, int BIAS>
__global__ __launch_bounds__(256) void gemm_k(
    const float* __restrict__ A, int lda, size_t saz,
    const float* __restrict__ B, int ldb,
    const float* __restrict__ bias,
    float* __restrict__ C, int ldc, size_t scz,
    int M, int N, int Kd) {
  A += (size_t)blockIdx.z * saz;
  C += (size_t)blockIdx.z * scz;
  __shared__ float As[32 * 65];  // transposed [k][m], pad 65
  __shared__ float Bs[32 * 68];  // [k][n], pad 68
  const int tid = threadIdx.x;
  const int m0 = blockIdx.y * 64, n0 = blockIdx.x * 64;
  const int tm = tid >> 4, tn = tid & 15;
  float acc[4][4] = {{0.f}};
  for (int k0 = 0; k0 < Kd; k0 += 32) {
    __syncthreads();
    #pragma unroll
    for (int it = 0; it < 2; ++it) {
      int m = (tid >> 3) + it * 32;
      int ks = (tid & 7) * 4;
      float v0 = 0.f, v1 = 0.f, v2 = 0.f, v3 = 0.f;
      int gm = m0 + m;
      if (gm < M) {
        const float* ap = A + (size_t)gm * lda + k0 + ks;
        int rem = Kd - (k0 + ks);
        if (rem >= 4) { v0 = ap[0]; v1 = ap[1]; v2 = ap[2]; v3 = ap[3]; }
        else { if (rem > 0) v0 = ap[0]; if (rem > 1) v1 = ap[1]; if (rem > 2) v2 = ap[2]; }
      }
      As[(ks + 0) * 65 + m] = v0;
      As[(ks + 1) * 65 + m] = v1;
      As[(ks + 2) * 65 + m] = v2;
      As[(ks + 3) * 65 + m] = v3;
    }
    {
      int k = tid >> 3;
      int nn = (tid & 7) * 8;
      int gk = k0 + k;
      if (gk < Kd && (n0 + nn + 8) <= N) {
        const float* p = B + (size_t)gk * ldb + n0 + nn;
        *(float4*)&Bs[k * 68 + nn]     = *(const float4*)p;
        *(float4*)&Bs[k * 68 + nn + 4] = *(const float4*)(p + 4);
      } else {
        #pragma unroll
        for (int j = 0; j < 8; ++j) {
          int gn = n0 + nn + j;
          Bs[k * 68 + nn + j] = (gk < Kd && gn < N) ? B[(size_t)gk * ldb + gn] : 0.f;
        }
      }
    }
    __syncthreads();
    #pragma unroll
    for (int kk = 0; kk < 32; ++kk) {
      float4 b = *(const float4*)&Bs[kk * 68 + tn * 4];
      #pragma unroll
      for (int r = 0; r < 4; ++r) {
        float a = As[kk * 65 + tm * 4 + r];
        acc[r][0] = fmaf(a, b.x, acc[r][0]);
        acc[r][1] = fmaf(a, b.y, acc[r][1]);
        acc[r][2] = fmaf(a, b.z, acc[r][2]);
        acc[r][3] = fmaf(a, b.w, acc[r][3]);
      }
    }
  }
  #pragma unroll
  for (int r = 0; r < 4; ++r) {
    int gm = m0 + tm * 4 + r;
    if (gm >= M) continue;
    #pragma unroll
    for (int c = 0; c < 4; ++c) {
      int gn = n0 + tn * 4 + c;
      if (gn >= N) continue;
      float v = acc[r][c];
      if (BIAS) v += bias[gn];
      if (ACT == 1) v = (v > 20.f) ? v : log1pf(__expf(v));
      float* cp = C + (size_t)gm * ldc + gn;
      if (ADD) *cp += v; else *cp = v;
    }
  }
}

// ---------------- depthwise causal conv (both directions) + silu ----------------
__global__ void conv_k(const float* __restrict__ XZ, const float* __restrict__ cw,
                       const float* __restrict__ cb, float* __restrict__ UC) {
  int idx = blockIdx.x * 256 + threadIdx.x;
  if (idx >= L_ * E_) return;
  int e = idx & (E_ - 1);
  int l = idx >> 9;
  float w0 = cw[0 * E_ + e], w1 = cw[1 * E_ + e];
  float w2 = cw[2 * E_ + e], w3 = cw[3 * E_ + e];
  float b = cb[e];
  float af = b, ab = b;
  #pragma unroll
  for (int k = 0; k < 4; ++k) {
    int j = l - 3 + k;
    if (j >= 0) {
      float wk = (k == 0) ? w0 : (k == 1) ? w1 : (k == 2) ? w2 : w3;
      af += wk * XZ[(size_t)j * 1024 + e];
      ab += wk * XZ[(size_t)(L_ - 1 - j) * 1024 + e];
    }
  }
  UC[idx] = siluf(af);
  UC[L_ * E_ + idx] = siluf(ab);
}

// ---------------- chunked selective scan (CH chunks of CL, LDS-staged) ----------------
// block: 256 thr = 16 e x 16 n; grid: dir(2) x chunk(CH) x eg(32)
__global__ __launch_bounds__(256) void scan1_k(
    const float* __restrict__ DTb, const float* __restrict__ UCb, const float* __restrict__ PRb,
    const float* __restrict__ alog, float* __restrict__ SP, float* __restrict__ SH) {
  int b = blockIdx.x;
  int eg = b & 31, chunk = (b >> 5) & (CH - 1), dir = b >> 10;
  int tid = threadIdx.x;
  int n = tid & 15, ep = tid >> 4;
  int e = eg * 16 + ep, e0 = eg * 16, l0 = chunk * CL;
  const float* dt = DTb + (size_t)dir * L_ * E_;
  const float* uc = UCb + (size_t)dir * L_ * E_;
  const float* pr = PRb + (size_t)dir * L_ * 48;
  __shared__ float dt_s[CL][16], uc_s[CL][16], B_s[CL][16];
  {
    int ls = tid >> 2, c4 = (tid & 3) * 4;
    int gl = l0 + ls;
    *(float4*)&dt_s[ls][c4] = *(const float4*)&dt[(size_t)gl * E_ + e0 + c4];
    *(float4*)&uc_s[ls][c4] = *(const float4*)&uc[(size_t)gl * E_ + e0 + c4];
    *(float4*)&B_s[ls][c4]  = *(const float4*)&pr[(size_t)gl * 48 + 16 + c4];
  }
  float A = -__expf(alog[e * 16 + n]);
  __syncthreads();
  float P = 1.f, h = 0.f;
  #pragma unroll 8
  for (int l = 0; l < CL; ++l) {
    float d = dt_s[l][ep];
    float a = __expf(d * A);
    float dub = d * uc_s[l][ep] * B_s[l][n];
    P *= a;
    h = fmaf(a, h, dub);
  }
  int idx = (dir * CH + chunk) * 8192 + e * 16 + n;
  SP[idx] = P;
  SH[idx] = h;
}

// carries across CH chunks per (dir,e,n); writes carry IN PLACE into SP.
__global__ void scan2_k(float* __restrict__ SP, const float* __restrict__ SH) {
  int idx = blockIdx.x * 256 + threadIdx.x;  // 2*8192
  if (idx >= 2 * E_ * 16) return;
  int dir = idx >> 13, en = idx & 8191;
  float c = 0.f;
  #pragma unroll
  for (int j = 0; j < CH; ++j) {
    int s = (dir * CH + j) * 8192 + en;
    float p = SP[s], hh = SH[s];
    SP[s] = c;
    c = p * c + hh;
  }
}

__global__ __launch_bounds__(256) void scan3_k(
    const float* __restrict__ DTb, const float* __restrict__ UCb, const float* __restrict__ PRb,
    const float* __restrict__ alog, const float* __restrict__ dp,
    const float* __restrict__ CIN, float* __restrict__ Y2) {
  int b = blockIdx.x;
  int eg = b & 31, chunk = (b >> 5) & (CH - 1), dir = b >> 10;
  int tid = threadIdx.x;
  int n = tid & 15, ep = tid >> 4;
  int e = eg * 16 + ep, e0 = eg * 16, l0 = chunk * CL;
  const float* dt = DTb + (size_t)dir * L_ * E_;
  const float* uc = UCb + (size_t)dir * L_ * E_;
  const float* pr = PRb + (size_t)dir * L_ * 48;
  float* Y = Y2 + (size_t)dir * L_ * E_;
  __shared__ float dt_s[CL][16], uc_s[CL][16], B_s[CL][16], C_s[CL][16], y_s[CL][16];
  {
    int ls = tid >> 2, c4 = (tid & 3) * 4;
    int gl = l0 + ls;
    *(float4*)&dt_s[ls][c4] = *(const float4*)&dt[(size_t)gl * E_ + e0 + c4];
    *(float4*)&uc_s[ls][c4] = *(const float4*)&uc[(size_t)gl * E_ + e0 + c4];
    *(float4*)&B_s[ls][c4]  = *(const float4*)&pr[(size_t)gl * 48 + 16 + c4];
    *(float4*)&C_s[ls][c4]  = *(const float4*)&pr[(size_t)gl * 48 + 32 + c4];
  }
  float A = -__expf(alog[e * 16 + n]);
  float D = dp[e];
  float h = CIN[(dir * CH + chunk) * 8192 + e * 16 + n];
  __syncthreads();
  #pragma unroll 8
  for (int l = 0; l < CL; ++l) {
    float d = dt_s[l][ep];
    float a = __expf(d * A);
    float dub = d * uc_s[l][ep] * B_s[l][n];
    h = fmaf(a, h, dub);
    float contrib = h * C_s[l][n];
    contrib += __shfl_xor(contrib, 1);
    contrib += __shfl_xor(contrib, 2);
    contrib += __shfl_xor(contrib, 4);
    contrib += __shfl_xor(contrib, 8);
    if (n == 0) y_s[l][ep] = fmaf(uc_s[l][ep], D, contrib);
  }
  __syncthreads();
  {
    int ls = tid >> 2, c4 = (tid & 3) * 4;
    int gl = l0 + ls;
    *(float4*)&Y[(size_t)gl * E_ + e0 + c4] = *(const float4*)&y_s[ls][c4];
  }
}

// ---------------- combine fwd+bwd, gate by silu(z) ----------------
__global__ void combine_k(const float* __restrict__ Y2, const float* __restrict__ XZ,
                          float* __restrict__ YG) {
  int idx = blockIdx.x * 256 + threadIdx.x;
  if (idx >= L_ * E_) return;
  int e = idx & (E_ - 1);
  int l = idx >> 9;
  float y = Y2[idx] + Y2[L_ * E_ + (size_t)(L_ - 1 - l) * E_ + e];
  float z = XZ[(size_t)l * 1024 + 512 + e];
  YG[idx] = y * siluf(z);
}

// ---------------- cross-attention core ----------------
__global__ __launch_bounds__(256) void attn_k(
    const float* __restrict__ Q, const float* __restrict__ te,
    const float* __restrict__ kw, const float* __restrict__ vw, const float* __restrict__ vb,
    float* __restrict__ AO) {
  int lane = threadIdx.x & 63, h = threadIdx.x >> 6;
  int l0 = blockIdx.x * 8;
  const float* kp0 = kw + (size_t)lane * DM_ + h * 64;
  const float* vp0 = vw + h * 64 + lane;
  float vbv = vb[h * 64 + lane];
  for (int p = 0; p < 8; ++p) {
    int l = l0 + p;
    float q = Q[(size_t)l * DM_ + h * 64 + lane];
    float g = 0.f;
    #pragma unroll
    for (int d0 = 0; d0 < 64; d0 += 4) {
      float4 r = *(const float4*)(kp0 + d0);
      g = fmaf(r.x, __shfl(q, d0 + 0), g);
      g = fmaf(r.y, __shfl(q, d0 + 1), g);
      g = fmaf(r.z, __shfl(q, d0 + 2), g);
      g = fmaf(r.w, __shfl(q, d0 + 3), g);
    }
    float tfv[8], pv[8];
    #pragma unroll
    for (int t = 0; t < 8; ++t) {
      tfv[t] = te[(size_t)t * L_ * 64 + (size_t)l * 64 + lane];
      pv[t] = tfv[t] * g;
    }
    #pragma unroll
    for (int t = 0; t < 8; ++t) {
      #pragma unroll
      for (int off = 1; off < 64; off <<= 1) pv[t] += __shfl_xor(pv[t], off);
    }
    float mx = pv[0];
    #pragma unroll
    for (int t = 1; t < 8; ++t) mx = fmaxf(mx, pv[t]);
    float s = 0.f;
    #pragma unroll
    for (int t = 0; t < 8; ++t) { pv[t] = __expf((pv[t] - mx) * 0.125f); s += pv[t]; }
    float inv = 1.f / s;
    float m = 0.f;
    #pragma unroll
    for (int t = 0; t < 8; ++t) m = fmaf(pv[t] * inv, tfv[t], m);
    float o = vbv;
    #pragma unroll 8
    for (int c = 0; c < 64; ++c)
      o = fmaf(__shfl(m, c), vp0[(size_t)c * DM_], o);
    AO[(size_t)l * DM_ + h * 64 + lane] = o;
  }
}

extern "C" void kernel_launch(void* const* d_in, const int* in_sizes, int n_in,
                              void* d_out, int out_size, void* d_ws, size_t ws_size,
                              hipStream_t stream) {
  (void)in_sizes; (void)n_in; (void)out_size; (void)ws_size;
  const float* x_in = (const float*)d_in[0];
  const float* te   = (const float*)d_in[1];
  const float* mnw  = (const float*)d_in[2];
  const float* ipw  = (const float*)d_in[3];
  const float* cw   = (const float*)d_in[4];
  const float* cb   = (const float*)d_in[5];
  const float* xpw  = (const float*)d_in[6];
  const float* dpw  = (const float*)d_in[7];
  const float* dpb  = (const float*)d_in[8];
  const float* alog = (const float*)d_in[9];
  const float* dprm = (const float*)d_in[10];
  const float* opw  = (const float*)d_in[11];
  const float* cnw  = (const float*)d_in[12];
  const float* qw   = (const float*)d_in[13];
  const float* qb   = (const float*)d_in[14];
  const float* kw   = (const float*)d_in[15];
  // d_in[16] = k_b: constant over tracks -> softmax-invariant, unused
  const float* vw   = (const float*)d_in[17];
  const float* vb   = (const float*)d_in[18];
  const float* ow   = (const float*)d_in[19];
  const float* ob   = (const float*)d_in[20];

  float* ws = (float*)d_ws;
  float* X   = ws + 0;          // 524288
  float* XZ  = ws + 524288;     // 2097152
  float* UC  = ws + 2621440;    // 2097152 (dir0, dir1)
  float* DTm = ws + 4718592;    // 2097152
  float* PR  = ws + 6815744;    // 196608
  float* Y2  = ws + 7012352;    // 2097152
  float* SP  = ws + 9109504;    // 524288 (P, then carries in-place)
  float* SH  = ws + 9633792;    // 524288  (end 10158080 floats = 40.6 MB)
  float* Hb  = UC + 1048576;    // alias UC dir1 (dead when used)
  float* YG  = UC;              // alias UC dir0 (dead after scan3)
  float* Qb  = DTm;             // alias DTm (dead in CA)
  float* AO  = DTm + 524288;

  hipMemcpyAsync(X, x_in, (size_t)L_ * DM_ * sizeof(float),
                 hipMemcpyDeviceToDevice, stream);

  for (int i = 0; i < 4; ++i) {
    rmsnorm_k<<<512, 256, 0, stream>>>(X, mnw + i * 256, Hb);
    gemm_k<0,0,0><<<dim3(16, 32), 256, 0, stream>>>(
        Hb, 256, 0, ipw + (size_t)i * 256 * 1024, 1024, nullptr, XZ, 1024, 0, L_, 1024, 256);
    conv_k<<<4096, 256, 0, stream>>>(XZ, cw + i * 4 * 512, cb + i * 512, UC);
    gemm_k<0,0,0><<<dim3(1, 32, 2), 256, 0, stream>>>(
        UC, 512, 1048576, xpw + (size_t)i * 512 * 48, 48, nullptr,
        PR, 48, 98304, L_, 48, 512);
    gemm_k<1,0,1><<<dim3(8, 32, 2), 256, 0, stream>>>(
        PR, 48, 98304, dpw + (size_t)i * 16 * 512, 512, dpb + i * 512,
        DTm, 512, 1048576, L_, 512, 16);
    scan1_k<<<2 * CH * 32, 256, 0, stream>>>(DTm, UC, PR, alog + (size_t)i * 512 * 16, SP, SH);
    scan2_k<<<64, 256, 0, stream>>>(SP, SH);
    scan3_k<<<2 * CH * 32, 256, 0, stream>>>(DTm, UC, PR, alog + (size_t)i * 512 * 16,
                                             dprm + i * 512, SP, Y2);
    combine_k<<<4096, 256, 0, stream>>>(Y2, XZ, YG);
    gemm_k<0,1,0><<<dim3(4, 32), 256, 0, stream>>>(
        YG, 512, 0, opw + (size_t)i * 512 * 256, 256, nullptr, X, 256, 0, L_, 256, 512);

    if (i == 1 || i == 3) {
      int j = (i == 1) ? 0 : 1;
      rmsnorm_k<<<512, 256, 0, stream>>>(X, cnw + j * 256, Hb);
      gemm_k<0,0,1><<<dim3(4, 32), 256, 0, stream>>>(
          Hb, 256, 0, qw + (size_t)j * 256 * 256, 256, qb + j * 256, Qb, 256, 0, L_, 256, 256);
      attn_k<<<256, 256, 0, stream>>>(Qb, te, kw + (size_t)j * 64 * 256,
                                      vw + (size_t)j * 64 * 256, vb + j * 256, AO);
      gemm_k<0,1,1><<<dim3(4, 32), 256, 0, stream>>>(
          AO, 256, 0, ow + (size_t)j * 256 * 256, 256, ob + j * 256, X, 256, 0, L_, 256, 256);
    }
  }

  hipMemcpyAsync(d_out, X, (size_t)L_ * DM_ * sizeof(float),
                 hipMemcpyDeviceToDevice, stream);
}

// Round 4
// 587.759 us; speedup vs baseline: 2.5381x; 1.5594x over previous
//
#include <hip/hip_runtime.h>
#include <hip/hip_bf16.h>

// MambaTower: B=1, L=2048, DM=256, E=512, N=16, R=16, K=4, NL=4, CA at layers 1,3
// fp32 tensors; GEMMs via bf16 MFMA (fp32 accumulate); dt_proj folded into x_proj.

constexpr int L_ = 2048, DM_ = 256, E_ = 512;
constexpr int CH = 32, CL = 64;  // scan chunks x chunk length

typedef __attribute__((ext_vector_type(8))) short bf16x8;
typedef __attribute__((ext_vector_type(4))) float f32x4;

__device__ __forceinline__ float siluf(float x) { return x / (1.f + __expf(-x)); }
__device__ __forceinline__ unsigned short f2b(float f) {
  union { float f; unsigned u; } x; x.f = f;
  unsigned r = x.u + 0x7fff + ((x.u >> 16) & 1);
  return (unsigned short)(r >> 16);
}

// ---------------- rmsnorm (row=256) ----------------
__global__ __launch_bounds__(256) void rmsnorm_k(const float* __restrict__ X,
                                                 const float* __restrict__ w,
                                                 float* __restrict__ Hout) {
  int lane = threadIdx.x & 63, wv = threadIdx.x >> 6;
  int row = blockIdx.x * 4 + wv;
  const float4 xv = *(const float4*)(X + (size_t)row * DM_ + lane * 4);
  float ss = xv.x * xv.x + xv.y * xv.y + xv.z * xv.z + xv.w * xv.w;
  #pragma unroll
  for (int off = 1; off < 64; off <<= 1) ss += __shfl_xor(ss, off);
  float sc = rsqrtf(ss * (1.f / DM_) + 1e-6f);
  const float4 wv4 = *(const float4*)(w + lane * 4);
  float4 o;
  o.x = xv.x * sc * wv4.x;
  o.y = xv.y * sc * wv4.y;
  o.z = xv.z * sc * wv4.z;
  o.w = xv.w * sc * wv4.w;
  *(float4*)(Hout + (size_t)row * DM_ + lane * 4) = o;
}

// ---------------- weight prep: transpose+cast fp32 [K][N] -> bf16 [N][K] ----------------
__global__ __launch_bounds__(256) void tcast_k(const float* __restrict__ in,
                                               unsigned short* __restrict__ out,
                                               int K, int N) {
  in  += (size_t)blockIdx.z * K * N;
  out += (size_t)blockIdx.z * K * N;
  __shared__ float t[32][33];
  int n0 = blockIdx.x * 32, k0 = blockIdx.y * 32;
  int tx = threadIdx.x & 31, ty = threadIdx.x >> 5;
  #pragma unroll
  for (int i = 0; i < 32; i += 8)
    t[ty + i][tx] = in[(size_t)(k0 + ty + i) * N + n0 + tx];
  __syncthreads();
  #pragma unroll
  for (int i = 0; i < 32; i += 8)
    out[(size_t)(n0 + ty + i) * K + k0 + tx] = f2b(t[tx][ty + i]);
}

// ---------------- weight prep: WXT[layer] = [Wdt^T | xwBC^T | 0pad] bf16 [576][512] ----------
// Wdt[k][n] = sum_r xw[k][r]*dw[r][n]  (k<512 input-dim, n<512 dt output-dim)
__global__ void wdt_k(const float* __restrict__ xpw, const float* __restrict__ dpw,
                      unsigned short* __restrict__ WXT) {
  int l = blockIdx.y;
  const float* xw = xpw + (size_t)l * 512 * 48;
  const float* dw = dpw + (size_t)l * 16 * 512;
  unsigned short* out = WXT + (size_t)l * 576 * 512;
  int b = blockIdx.x, t = threadIdx.x;
  if (b < 1024) {
    int idx = b * 256 + t;
    int k = idx & 511, n = idx >> 9;
    float s = 0.f;
    #pragma unroll
    for (int r = 0; r < 16; ++r) s = fmaf(xw[k * 48 + r], dw[r * 512 + n], s);
    out[(size_t)n * 512 + k] = f2b(s);
  } else if (b < 1088) {
    int idx = (b - 1024) * 256 + t;  // 32*512
    int k = idx & 511, j = idx >> 9;
    out[(size_t)(512 + j) * 512 + k] = f2b(xw[k * 48 + 16 + j]);
  } else {
    int idx = (b - 1088) * 256 + t;
    int k = idx & 511, j = idx >> 9;
    out[(size_t)(544 + j) * 512 + k] = 0;
  }
}

// ---------------- MFMA GEMM: C[2048 x N] = op(A[2048 x K] * BT^T) ----------------
// A fp32 row-major (lda), BT bf16 [N][K] (pre-transposed), C fp32 (ldc).
// MODE: 0 store | 1 softplus(v+bias[gn]) for gn<512 else store (fused dt) |
//       2 C+=v | 3 store v+bias | 4 C+=v+bias
template<int MODE>
__global__ __launch_bounds__(256) void mgemm_k(
    const float* __restrict__ A, int lda, size_t saz,
    const unsigned short* __restrict__ BT,
    const float* __restrict__ bias,
    float* __restrict__ C, int ldc, size_t scz,
    int Kd) {
  A += (size_t)blockIdx.z * saz;
  C += (size_t)blockIdx.z * scz;
  __shared__ unsigned short Als[64 * 64];
  __shared__ unsigned short Bls[64 * 64];
  const int tid = threadIdx.x;
  const int lane = tid & 63, wave = tid >> 6;
  const int wm = wave >> 1, wn = wave & 1;
  const int m0 = blockIdx.y * 64, n0 = blockIdx.x * 64;
  const int srow = tid >> 2, sc = tid & 3;
  const unsigned swz = (unsigned)((srow & 7) << 4);
  f32x4 acc[2][2] = {};
  for (int k0 = 0; k0 < Kd; k0 += 64) {
    __syncthreads();
    // stage A: 16 fp32 -> bf16 per thread
    {
      const float* ap = A + (size_t)(m0 + srow) * lda + k0 + sc * 16;
      #pragma unroll
      for (int i = 0; i < 4; ++i) {
        float4 v = *(const float4*)(ap + i * 4);
        uint2 p;
        p.x = (unsigned)f2b(v.x) | ((unsigned)f2b(v.y) << 16);
        p.y = (unsigned)f2b(v.z) | ((unsigned)f2b(v.w) << 16);
        unsigned off = (unsigned)(srow * 128 + (sc * 16 + i * 4) * 2) ^ swz;
        *(uint2*)((char*)Als + off) = p;
      }
    }
    // stage B: 16 bf16 per thread (2 x 16B)
    {
      const unsigned short* bp = BT + (size_t)(n0 + srow) * Kd + k0 + sc * 8;
      #pragma unroll
      for (int i = 0; i < 2; ++i) {
        uint4 v = *(const uint4*)(bp + i * 32);
        unsigned off = (unsigned)(srow * 128 + (sc * 8 + i * 32) * 2) ^ swz;
        *(uint4*)((char*)Bls + off) = v;
      }
    }
    __syncthreads();
    #pragma unroll
    for (int ks = 0; ks < 64; ks += 32) {
      bf16x8 af[2], bfr[2];
      #pragma unroll
      for (int mi = 0; mi < 2; ++mi) {
        int row = wm * 32 + mi * 16 + (lane & 15);
        unsigned off = (unsigned)(row * 128 + (ks + (lane >> 4) * 8) * 2) ^ ((unsigned)((row & 7) << 4));
        af[mi] = *(const bf16x8*)((const char*)Als + off);
      }
      #pragma unroll
      for (int ni = 0; ni < 2; ++ni) {
        int row = wn * 32 + ni * 16 + (lane & 15);
        unsigned off = (unsigned)(row * 128 + (ks + (lane >> 4) * 8) * 2) ^ ((unsigned)((row & 7) << 4));
        bfr[ni] = *(const bf16x8*)((const char*)Bls + off);
      }
      #pragma unroll
      for (int mi = 0; mi < 2; ++mi)
        #pragma unroll
        for (int ni = 0; ni < 2; ++ni)
          acc[mi][ni] = __builtin_amdgcn_mfma_f32_16x16x32_bf16(af[mi], bfr[ni], acc[mi][ni], 0, 0, 0);
    }
  }
  // epilogue: D row=(lane>>4)*4+reg, col=lane&15
  #pragma unroll
  for (int mi = 0; mi < 2; ++mi) {
    #pragma unroll
    for (int ni = 0; ni < 2; ++ni) {
      int gm = m0 + wm * 32 + mi * 16 + (lane >> 4) * 4;
      int gn = n0 + wn * 32 + ni * 16 + (lane & 15);
      float bv = (MODE == 3 || MODE == 4) ? bias[gn] : 0.f;
      #pragma unroll
      for (int r = 0; r < 4; ++r) {
        float x = acc[mi][ni][r];
        if (MODE == 1) {
          if (gn < 512) {
            x += bias[gn];
            x = (x > 20.f) ? x : log1pf(__expf(x));
          }
        }
        if (MODE == 3 || MODE == 4) x += bv;
        float* cp = C + (size_t)(gm + r) * ldc + gn;
        if (MODE == 2 || MODE == 4) *cp += x; else *cp = x;
      }
    }
  }
}

// ---------------- depthwise causal conv (both directions) + silu ----------------
__global__ void conv_k(const float* __restrict__ XZ, const float* __restrict__ cw,
                       const float* __restrict__ cb, float* __restrict__ UC) {
  int idx = blockIdx.x * 256 + threadIdx.x;
  if (idx >= L_ * E_) return;
  int e = idx & (E_ - 1);
  int l = idx >> 9;
  float w0 = cw[0 * E_ + e], w1 = cw[1 * E_ + e];
  float w2 = cw[2 * E_ + e], w3 = cw[3 * E_ + e];
  float b = cb[e];
  float af = b, ab = b;
  #pragma unroll
  for (int k = 0; k < 4; ++k) {
    int j = l - 3 + k;
    if (j >= 0) {
      float wk = (k == 0) ? w0 : (k == 1) ? w1 : (k == 2) ? w2 : w3;
      af += wk * XZ[(size_t)j * 1024 + e];
      ab += wk * XZ[(size_t)(L_ - 1 - j) * 1024 + e];
    }
  }
  UC[idx] = siluf(af);
  UC[L_ * E_ + idx] = siluf(ab);
}

// ---------------- chunked selective scan (dt/B/C read from PRD, ld 576) ----------------
__global__ __launch_bounds__(256) void scan1_k(
    const float* __restrict__ PRDb, const float* __restrict__ UCb,
    const float* __restrict__ alog, float* __restrict__ SP, float* __restrict__ SH) {
  int b = blockIdx.x;
  int eg = b & 31, chunk = (b >> 5) & (CH - 1), dir = b >> 10;
  int tid = threadIdx.x;
  int n = tid & 15, ep = tid >> 4;
  int e = eg * 16 + ep, e0 = eg * 16, l0 = chunk * CL;
  const float* prd = PRDb + (size_t)dir * L_ * 576;
  const float* uc = UCb + (size_t)dir * L_ * E_;
  __shared__ float dt_s[CL][16], uc_s[CL][16], B_s[CL][16];
  {
    int ls = tid >> 2, c4 = (tid & 3) * 4;
    int gl = l0 + ls;
    *(float4*)&dt_s[ls][c4] = *(const float4*)&prd[(size_t)gl * 576 + e0 + c4];
    *(float4*)&uc_s[ls][c4] = *(const float4*)&uc[(size_t)gl * E_ + e0 + c4];
    *(float4*)&B_s[ls][c4]  = *(const float4*)&prd[(size_t)gl * 576 + 512 + c4];
  }
  float A = -__expf(alog[e * 16 + n]);
  __syncthreads();
  float P = 1.f, h = 0.f;
  #pragma unroll 8
  for (int l = 0; l < CL; ++l) {
    float d = dt_s[l][ep];
    float a = __expf(d * A);
    float dub = d * uc_s[l][ep] * B_s[l][n];
    P *= a;
    h = fmaf(a, h, dub);
  }
  int idx = (dir * CH + chunk) * 8192 + e * 16 + n;
  SP[idx] = P;
  SH[idx] = h;
}

__global__ void scan2_k(float* __restrict__ SP, const float* __restrict__ SH) {
  int idx = blockIdx.x * 256 + threadIdx.x;  // 2*8192
  if (idx >= 2 * E_ * 16) return;
  int dir = idx >> 13, en = idx & 8191;
  float c = 0.f;
  #pragma unroll
  for (int j = 0; j < CH; ++j) {
    int s = (dir * CH + j) * 8192 + en;
    float p = SP[s], hh = SH[s];
    SP[s] = c;
    c = p * c + hh;
  }
}

__global__ __launch_bounds__(256) void scan3_k(
    const float* __restrict__ PRDb, const float* __restrict__ UCb,
    const float* __restrict__ alog, const float* __restrict__ dp,
    const float* __restrict__ CIN, float* __restrict__ Y2) {
  int b = blockIdx.x;
  int eg = b & 31, chunk = (b >> 5) & (CH - 1), dir = b >> 10;
  int tid = threadIdx.x;
  int n = tid & 15, ep = tid >> 4;
  int e = eg * 16 + ep, e0 = eg * 16, l0 = chunk * CL;
  const float* prd = PRDb + (size_t)dir * L_ * 576;
  const float* uc = UCb + (size_t)dir * L_ * E_;
  float* Y = Y2 + (size_t)dir * L_ * E_;
  __shared__ float dt_s[CL][16], uc_s[CL][16], B_s[CL][16], C_s[CL][16], y_s[CL][16];
  {
    int ls = tid >> 2, c4 = (tid & 3) * 4;
    int gl = l0 + ls;
    *(float4*)&dt_s[ls][c4] = *(const float4*)&prd[(size_t)gl * 576 + e0 + c4];
    *(float4*)&uc_s[ls][c4] = *(const float4*)&uc[(size_t)gl * E_ + e0 + c4];
    *(float4*)&B_s[ls][c4]  = *(const float4*)&prd[(size_t)gl * 576 + 512 + c4];
    *(float4*)&C_s[ls][c4]  = *(const float4*)&prd[(size_t)gl * 576 + 528 + c4];
  }
  float A = -__expf(alog[e * 16 + n]);
  float D = dp[e];
  float h = CIN[(dir * CH + chunk) * 8192 + e * 16 + n];
  __syncthreads();
  #pragma unroll 8
  for (int l = 0; l < CL; ++l) {
    float d = dt_s[l][ep];
    float a = __expf(d * A);
    float dub = d * uc_s[l][ep] * B_s[l][n];
    h = fmaf(a, h, dub);
    float contrib = h * C_s[l][n];
    contrib += __shfl_xor(contrib, 1);
    contrib += __shfl_xor(contrib, 2);
    contrib += __shfl_xor(contrib, 4);
    contrib += __shfl_xor(contrib, 8);
    if (n == 0) y_s[l][ep] = fmaf(uc_s[l][ep], D, contrib);
  }
  __syncthreads();
  {
    int ls = tid >> 2, c4 = (tid & 3) * 4;
    int gl = l0 + ls;
    *(float4*)&Y[(size_t)gl * E_ + e0 + c4] = *(const float4*)&y_s[ls][c4];
  }
}

// ---------------- combine fwd+bwd, gate by silu(z) ----------------
__global__ void combine_k(const float* __restrict__ Y2, const float* __restrict__ XZ,
                          float* __restrict__ YG) {
  int idx = blockIdx.x * 256 + threadIdx.x;
  if (idx >= L_ * E_) return;
  int e = idx & (E_ - 1);
  int l = idx >> 9;
  float y = Y2[idx] + Y2[L_ * E_ + (size_t)(L_ - 1 - l) * E_ + e];
  float z = XZ[(size_t)l * 1024 + 512 + e];
  YG[idx] = y * siluf(z);
}

// ---------------- cross-attention core ----------------
__global__ __launch_bounds__(256) void attn_k(
    const float* __restrict__ Q, const float* __restrict__ te,
    const float* __restrict__ kw, const float* __restrict__ vw, const float* __restrict__ vb,
    float* __restrict__ AO) {
  int lane = threadIdx.x & 63, h = threadIdx.x >> 6;
  int l0 = blockIdx.x * 8;
  const float* kp0 = kw + (size_t)lane * DM_ + h * 64;
  const float* vp0 = vw + h * 64 + lane;
  float vbv = vb[h * 64 + lane];
  for (int p = 0; p < 8; ++p) {
    int l = l0 + p;
    float q = Q[(size_t)l * DM_ + h * 64 + lane];
    float g = 0.f;
    #pragma unroll
    for (int d0 = 0; d0 < 64; d0 += 4) {
      float4 r = *(const float4*)(kp0 + d0);
      g = fmaf(r.x, __shfl(q, d0 + 0), g);
      g = fmaf(r.y, __shfl(q, d0 + 1), g);
      g = fmaf(r.z, __shfl(q, d0 + 2), g);
      g = fmaf(r.w, __shfl(q, d0 + 3), g);
    }
    float tfv[8], pv[8];
    #pragma unroll
    for (int t = 0; t < 8; ++t) {
      tfv[t] = te[(size_t)t * L_ * 64 + (size_t)l * 64 + lane];
      pv[t] = tfv[t] * g;
    }
    #pragma unroll
    for (int t = 0; t < 8; ++t) {
      #pragma unroll
      for (int off = 1; off < 64; off <<= 1) pv[t] += __shfl_xor(pv[t], off);
    }
    float mx = pv[0];
    #pragma unroll
    for (int t = 1; t < 8; ++t) mx = fmaxf(mx, pv[t]);
    float s = 0.f;
    #pragma unroll
    for (int t = 0; t < 8; ++t) { pv[t] = __expf((pv[t] - mx) * 0.125f); s += pv[t]; }
    float inv = 1.f / s;
    float m = 0.f;
    #pragma unroll
    for (int t = 0; t < 8; ++t) m = fmaf(pv[t] * inv, tfv[t], m);
    float o = vbv;
    #pragma unroll 8
    for (int c = 0; c < 64; ++c)
      o = fmaf(__shfl(m, c), vp0[(size_t)c * DM_], o);
    AO[(size_t)l * DM_ + h * 64 + lane] = o;
  }
}

extern "C" void kernel_launch(void* const* d_in, const int* in_sizes, int n_in,
                              void* d_out, int out_size, void* d_ws, size_t ws_size,
                              hipStream_t stream) {
  (void)in_sizes; (void)n_in; (void)out_size; (void)ws_size;
  const float* x_in = (const float*)d_in[0];
  const float* te   = (const float*)d_in[1];
  const float* mnw  = (const float*)d_in[2];
  const float* ipw  = (const float*)d_in[3];
  const float* cw   = (const float*)d_in[4];
  const float* cb   = (const float*)d_in[5];
  const float* xpw  = (const float*)d_in[6];
  const float* dpw  = (const float*)d_in[7];
  const float* dpb  = (const float*)d_in[8];
  const float* alog = (const float*)d_in[9];
  const float* dprm = (const float*)d_in[10];
  const float* opw  = (const float*)d_in[11];
  const float* cnw  = (const float*)d_in[12];
  const float* qw   = (const float*)d_in[13];
  const float* qb   = (const float*)d_in[14];
  const float* kw   = (const float*)d_in[15];
  // d_in[16] = k_b: constant over tracks -> softmax-invariant, unused
  const float* vw   = (const float*)d_in[17];
  const float* vb   = (const float*)d_in[18];
  const float* ow   = (const float*)d_in[19];
  const float* ob   = (const float*)d_in[20];

  float* ws = (float*)d_ws;
  float* X   = ws + 0;          // 524288
  float* XZ  = ws + 524288;     // 2097152
  float* UC  = ws + 2621440;    // 2097152 (dir0, dir1)
  float* PRD = ws + 4718592;    // 2359296 = 2 x 2048 x 576
  float* Y2  = ws + 7077888;    // 2097152
  float* SP  = ws + 9175040;    // 524288
  float* SH  = ws + 9699328;    // 524288
  unsigned short* ipwT = (unsigned short*)(ws + 10223616);  // 4x1024x256 bf16 (524288 fl)
  unsigned short* WXT  = (unsigned short*)(ws + 10747904);  // 4x576x512 bf16 (589824 fl)
  unsigned short* opwT = (unsigned short*)(ws + 11337728);  // 4x256x512 bf16 (262144 fl)
  unsigned short* qwT  = (unsigned short*)(ws + 11599872);  // 2x256x256 bf16 (65536 fl)
  unsigned short* owT  = (unsigned short*)(ws + 11665408);  // 2x256x256 bf16 (65536 fl)
  // end: 11730944 floats = 46.9 MB
  float* Hb = UC + 1048576;  // alias UC dir1 (dead when used)
  float* YG = UC;            // alias UC dir0 (dead after scan3)
  float* Qb = SP;            // alias SP (dead in CA phase)
  float* AO = SH;            // alias SH (dead in CA phase), 524288 fl

  // weight prep (cheap, once per launch)
  tcast_k<<<dim3(32, 8, 4), 256, 0, stream>>>(ipw, ipwT, 256, 1024);
  tcast_k<<<dim3(8, 16, 4), 256, 0, stream>>>(opw, opwT, 512, 256);
  tcast_k<<<dim3(8, 8, 2), 256, 0, stream>>>(qw, qwT, 256, 256);
  tcast_k<<<dim3(8, 8, 2), 256, 0, stream>>>(ow, owT, 256, 256);
  wdt_k<<<dim3(1152, 4), 256, 0, stream>>>(xpw, dpw, WXT);

  hipMemcpyAsync(X, x_in, (size_t)L_ * DM_ * sizeof(float),
                 hipMemcpyDeviceToDevice, stream);

  for (int i = 0; i < 4; ++i) {
    rmsnorm_k<<<512, 256, 0, stream>>>(X, mnw + i * 256, Hb);
    mgemm_k<0><<<dim3(16, 32, 1), 256, 0, stream>>>(
        Hb, 256, 0, ipwT + (size_t)i * 1024 * 256, nullptr, XZ, 1024, 0, 256);
    conv_k<<<4096, 256, 0, stream>>>(XZ, cw + i * 4 * 512, cb + i * 512, UC);
    mgemm_k<1><<<dim3(9, 32, 2), 256, 0, stream>>>(
        UC, 512, 1048576, WXT + (size_t)i * 576 * 512, dpb + i * 512,
        PRD, 576, 1179648, 512);
    scan1_k<<<2 * CH * 32, 256, 0, stream>>>(PRD, UC, alog + (size_t)i * 512 * 16, SP, SH);
    scan2_k<<<64, 256, 0, stream>>>(SP, SH);
    scan3_k<<<2 * CH * 32, 256, 0, stream>>>(PRD, UC, alog + (size_t)i * 512 * 16,
                                             dprm + i * 512, SP, Y2);
    combine_k<<<4096, 256, 0, stream>>>(Y2, XZ, YG);
    mgemm_k<2><<<dim3(4, 32, 1), 256, 0, stream>>>(
        YG, 512, 0, opwT + (size_t)i * 256 * 512, nullptr, X, 256, 0, 512);

    if (i == 1 || i == 3) {
      int j = (i == 1) ? 0 : 1;
      rmsnorm_k<<<512, 256, 0, stream>>>(X, cnw + j * 256, Hb);
      mgemm_k<3><<<dim3(4, 32, 1), 256, 0, stream>>>(
          Hb, 256, 0, qwT + (size_t)j * 256 * 256, qb + j * 256, Qb, 256, 0, 256);
      attn_k<<<256, 256, 0, stream>>>(Qb, te, kw + (size_t)j * 64 * 256,
                                      vw + (size_t)j * 64 * 256, vb + j * 256, AO);
      mgemm_k<4><<<dim3(4, 32, 1), 256, 0, stream>>>(
          AO, 256, 0, owT + (size_t)j * 256 * 256, ob + j * 256, X, 256, 0, 256);
    }
  }

  hipMemcpyAsync(d_out, X, (size_t)L_ * DM_ * sizeof(float),
                 hipMemcpyDeviceToDevice, stream);
}

// Round 5
// 505.307 us; speedup vs baseline: 2.9522x; 1.1632x over previous
//
#include <hip/hip_runtime.h>
#include <hip/hip_bf16.h>

// MambaTower: B=1, L=2048, DM=256, E=512, N=16, R=16, K=4, NL=4, CA at layers 1,3
// fp32 tensors; GEMMs via bf16 MFMA; dt_proj folded into x_proj.
// Scan: thread <-> (dir,e), 16 SSM states in registers, no cross-lane ops.

constexpr int L_ = 2048, DM_ = 256, E_ = 512;
constexpr int CH = 64, CL = 32;  // scan chunks x chunk length (CH*CL == L_)

typedef __attribute__((ext_vector_type(8))) short bf16x8;
typedef __attribute__((ext_vector_type(4))) float f32x4;

__device__ __forceinline__ float siluf(float x) { return x / (1.f + __expf(-x)); }
__device__ __forceinline__ unsigned short f2b(float f) {
  union { float f; unsigned u; } x; x.f = f;
  unsigned r = x.u + 0x7fff + ((x.u >> 16) & 1);
  return (unsigned short)(r >> 16);
}

// ---------------- rmsnorm (row=256) ----------------
__global__ __launch_bounds__(256) void rmsnorm_k(const float* __restrict__ X,
                                                 const float* __restrict__ w,
                                                 float* __restrict__ Hout) {
  int lane = threadIdx.x & 63, wv = threadIdx.x >> 6;
  int row = blockIdx.x * 4 + wv;
  const float4 xv = *(const float4*)(X + (size_t)row * DM_ + lane * 4);
  float ss = xv.x * xv.x + xv.y * xv.y + xv.z * xv.z + xv.w * xv.w;
  #pragma unroll
  for (int off = 1; off < 64; off <<= 1) ss += __shfl_xor(ss, off);
  float sc = rsqrtf(ss * (1.f / DM_) + 1e-6f);
  const float4 wv4 = *(const float4*)(w + lane * 4);
  float4 o;
  o.x = xv.x * sc * wv4.x;
  o.y = xv.y * sc * wv4.y;
  o.z = xv.z * sc * wv4.z;
  o.w = xv.w * sc * wv4.w;
  *(float4*)(Hout + (size_t)row * DM_ + lane * 4) = o;
}

// ---------------- weight prep: transpose+cast fp32 [K][N] -> bf16 [N][K] ----------------
__global__ __launch_bounds__(256) void tcast_k(const float* __restrict__ in,
                                               unsigned short* __restrict__ out,
                                               int K, int N) {
  in  += (size_t)blockIdx.z * K * N;
  out += (size_t)blockIdx.z * K * N;
  __shared__ float t[32][33];
  int n0 = blockIdx.x * 32, k0 = blockIdx.y * 32;
  int tx = threadIdx.x & 31, ty = threadIdx.x >> 5;
  #pragma unroll
  for (int i = 0; i < 32; i += 8)
    t[ty + i][tx] = in[(size_t)(k0 + ty + i) * N + n0 + tx];
  __syncthreads();
  #pragma unroll
  for (int i = 0; i < 32; i += 8)
    out[(size_t)(n0 + ty + i) * K + k0 + tx] = f2b(t[tx][ty + i]);
}

// ---------------- weight prep: WXT[layer] = [Wdt^T | xwBC^T | 0pad] bf16 [576][512] ----------
__global__ void wdt_k(const float* __restrict__ xpw, const float* __restrict__ dpw,
                      unsigned short* __restrict__ WXT) {
  int l = blockIdx.y;
  const float* xw = xpw + (size_t)l * 512 * 48;
  const float* dw = dpw + (size_t)l * 16 * 512;
  unsigned short* out = WXT + (size_t)l * 576 * 512;
  int b = blockIdx.x, t = threadIdx.x;
  if (b < 1024) {
    int idx = b * 256 + t;
    int k = idx & 511, n = idx >> 9;
    float s = 0.f;
    #pragma unroll
    for (int r = 0; r < 16; ++r) s = fmaf(xw[k * 48 + r], dw[r * 512 + n], s);
    out[(size_t)n * 512 + k] = f2b(s);
  } else if (b < 1088) {
    int idx = (b - 1024) * 256 + t;
    int k = idx & 511, j = idx >> 9;
    out[(size_t)(512 + j) * 512 + k] = f2b(xw[k * 48 + 16 + j]);
  } else {
    int idx = (b - 1088) * 256 + t;
    int k = idx & 511, j = idx >> 9;
    out[(size_t)(544 + j) * 512 + k] = 0;
  }
}

// ---------------- MFMA GEMM: C[2048 x N] = op(A[2048 x K] * BT^T) ----------------
// MODE: 0 store | 1 softplus(v+bias) for gn<512 else store | 2 C+=v | 3 store v+bias | 4 C+=v+bias
template<int MODE>
__global__ __launch_bounds__(256) void mgemm_k(
    const float* __restrict__ A, int lda, size_t saz,
    const unsigned short* __restrict__ BT,
    const float* __restrict__ bias,
    float* __restrict__ C, int ldc, size_t scz,
    int Kd) {
  A += (size_t)blockIdx.z * saz;
  C += (size_t)blockIdx.z * scz;
  __shared__ unsigned short Als[64 * 64];
  __shared__ unsigned short Bls[64 * 64];
  const int tid = threadIdx.x;
  const int lane = tid & 63, wave = tid >> 6;
  const int wm = wave >> 1, wn = wave & 1;
  const int m0 = blockIdx.y * 64, n0 = blockIdx.x * 64;
  const int srow = tid >> 2, sc = tid & 3;
  const unsigned swz = (unsigned)((srow & 7) << 4);
  f32x4 acc[2][2] = {};
  for (int k0 = 0; k0 < Kd; k0 += 64) {
    __syncthreads();
    {
      const float* ap = A + (size_t)(m0 + srow) * lda + k0 + sc * 16;
      #pragma unroll
      for (int i = 0; i < 4; ++i) {
        float4 v = *(const float4*)(ap + i * 4);
        uint2 p;
        p.x = (unsigned)f2b(v.x) | ((unsigned)f2b(v.y) << 16);
        p.y = (unsigned)f2b(v.z) | ((unsigned)f2b(v.w) << 16);
        unsigned off = (unsigned)(srow * 128 + (sc * 16 + i * 4) * 2) ^ swz;
        *(uint2*)((char*)Als + off) = p;
      }
    }
    {
      const unsigned short* bp = BT + (size_t)(n0 + srow) * Kd + k0 + sc * 8;
      #pragma unroll
      for (int i = 0; i < 2; ++i) {
        uint4 v = *(const uint4*)(bp + i * 32);
        unsigned off = (unsigned)(srow * 128 + (sc * 8 + i * 32) * 2) ^ swz;
        *(uint4*)((char*)Bls + off) = v;
      }
    }
    __syncthreads();
    #pragma unroll
    for (int ks = 0; ks < 64; ks += 32) {
      bf16x8 af[2], bfr[2];
      #pragma unroll
      for (int mi = 0; mi < 2; ++mi) {
        int row = wm * 32 + mi * 16 + (lane & 15);
        unsigned off = (unsigned)(row * 128 + (ks + (lane >> 4) * 8) * 2) ^ ((unsigned)((row & 7) << 4));
        af[mi] = *(const bf16x8*)((const char*)Als + off);
      }
      #pragma unroll
      for (int ni = 0; ni < 2; ++ni) {
        int row = wn * 32 + ni * 16 + (lane & 15);
        unsigned off = (unsigned)(row * 128 + (ks + (lane >> 4) * 8) * 2) ^ ((unsigned)((row & 7) << 4));
        bfr[ni] = *(const bf16x8*)((const char*)Bls + off);
      }
      #pragma unroll
      for (int mi = 0; mi < 2; ++mi)
        #pragma unroll
        for (int ni = 0; ni < 2; ++ni)
          acc[mi][ni] = __builtin_amdgcn_mfma_f32_16x16x32_bf16(af[mi], bfr[ni], acc[mi][ni], 0, 0, 0);
    }
  }
  #pragma unroll
  for (int mi = 0; mi < 2; ++mi) {
    #pragma unroll
    for (int ni = 0; ni < 2; ++ni) {
      int gm = m0 + wm * 32 + mi * 16 + (lane >> 4) * 4;
      int gn = n0 + wn * 32 + ni * 16 + (lane & 15);
      float bv = (MODE == 3 || MODE == 4) ? bias[gn] : 0.f;
      #pragma unroll
      for (int r = 0; r < 4; ++r) {
        float x = acc[mi][ni][r];
        if (MODE == 1) {
          if (gn < 512) {
            x += bias[gn];
            x = (x > 20.f) ? x : log1pf(__expf(x));
          }
        }
        if (MODE == 3 || MODE == 4) x += bv;
        float* cp = C + (size_t)(gm + r) * ldc + gn;
        if (MODE == 2 || MODE == 4) *cp += x; else *cp = x;
      }
    }
  }
}

// ---------------- depthwise causal conv (both directions) + silu ----------------
__global__ void conv_k(const float* __restrict__ XZ, const float* __restrict__ cw,
                       const float* __restrict__ cb, float* __restrict__ UC) {
  int idx = blockIdx.x * 256 + threadIdx.x;
  if (idx >= L_ * E_) return;
  int e = idx & (E_ - 1);
  int l = idx >> 9;
  float w0 = cw[0 * E_ + e], w1 = cw[1 * E_ + e];
  float w2 = cw[2 * E_ + e], w3 = cw[3 * E_ + e];
  float b = cb[e];
  float af = b, ab = b;
  #pragma unroll
  for (int k = 0; k < 4; ++k) {
    int j = l - 3 + k;
    if (j >= 0) {
      float wk = (k == 0) ? w0 : (k == 1) ? w1 : (k == 2) ? w2 : w3;
      af += wk * XZ[(size_t)j * 1024 + e];
      ab += wk * XZ[(size_t)(L_ - 1 - j) * 1024 + e];
    }
  }
  UC[idx] = siluf(af);
  UC[L_ * E_ + idx] = siluf(ab);
}

// ---------------- selective scan: thread=(dir,e), 16 states in regs ----------------
// grid.x = eg(2) + chunk(CH)*2 + dir*CH*2; block 256 (e = eg*256 + tid)
__global__ __launch_bounds__(256) void scan1_k(
    const float* __restrict__ PRDb, const float* __restrict__ UCb,
    const float* __restrict__ alog, float* __restrict__ SP, float* __restrict__ SH) {
  int b = blockIdx.x;
  int eg = b & 1, chunk = (b >> 1) & (CH - 1), dir = b >> 7;
  int e = eg * 256 + threadIdx.x;
  int l0 = chunk * CL;
  const float* prd = PRDb + (size_t)dir * L_ * 576;
  const float* ucp = UCb + (size_t)dir * L_ * E_;
  __shared__ float B_s[CL][16];
  for (int i = threadIdx.x; i < CL * 16; i += 256) {
    int l = i >> 4, n = i & 15;
    B_s[l][n] = prd[(size_t)(l0 + l) * 576 + 512 + n];
  }
  float A[16];
  #pragma unroll
  for (int n = 0; n < 16; n += 4) {
    float4 v = *(const float4*)&alog[(size_t)e * 16 + n];
    A[n] = -__expf(v.x); A[n+1] = -__expf(v.y); A[n+2] = -__expf(v.z); A[n+3] = -__expf(v.w);
  }
  float h[16];
  #pragma unroll
  for (int n = 0; n < 16; ++n) h[n] = 0.f;
  float sd = 0.f;
  __syncthreads();
  #pragma unroll
  for (int t = 0; t < CL; t += 8) {
    float d[8], u[8];
    #pragma unroll
    for (int j = 0; j < 8; ++j) {
      d[j] = prd[(size_t)(l0 + t + j) * 576 + e];
      u[j] = ucp[(size_t)(l0 + t + j) * E_ + e];
    }
    #pragma unroll
    for (int j = 0; j < 8; ++j) {
      float du = d[j] * u[j];
      sd += d[j];
      #pragma unroll
      for (int n = 0; n < 16; ++n)
        h[n] = fmaf(__expf(d[j] * A[n]), h[n], du * B_s[t + j][n]);
    }
  }
  size_t idx = ((size_t)(dir * CH + chunk) * 8192) + (size_t)e * 16;
  #pragma unroll
  for (int n = 0; n < 16; ++n) {
    SP[idx + n] = __expf(A[n] * sd);  // product of per-step decay factors
    SH[idx + n] = h[n];
  }
}

// carries across CH chunks per (dir,e,n); writes carry IN PLACE into SP.
__global__ void scan2_k(float* __restrict__ SP, const float* __restrict__ SH) {
  int idx = blockIdx.x * 256 + threadIdx.x;  // 2*8192
  if (idx >= 2 * E_ * 16) return;
  int dir = idx >> 13, en = idx & 8191;
  float c = 0.f;
  #pragma unroll
  for (int j = 0; j < CH; ++j) {
    size_t s = (size_t)(dir * CH + j) * 8192 + en;
    float p = SP[s], hh = SH[s];
    SP[s] = c;
    c = p * c + hh;
  }
}

__global__ __launch_bounds__(256) void scan3_k(
    const float* __restrict__ PRDb, const float* __restrict__ UCb,
    const float* __restrict__ alog, const float* __restrict__ dp,
    const float* __restrict__ CIN, float* __restrict__ Y2) {
  int b = blockIdx.x;
  int eg = b & 1, chunk = (b >> 1) & (CH - 1), dir = b >> 7;
  int e = eg * 256 + threadIdx.x;
  int l0 = chunk * CL;
  const float* prd = PRDb + (size_t)dir * L_ * 576;
  const float* ucp = UCb + (size_t)dir * L_ * E_;
  float* Y = Y2 + (size_t)dir * L_ * E_;
  __shared__ float B_s[CL][16], C_s[CL][16];
  for (int i = threadIdx.x; i < CL * 16; i += 256) {
    int l = i >> 4, n = i & 15;
    B_s[l][n] = prd[(size_t)(l0 + l) * 576 + 512 + n];
    C_s[l][n] = prd[(size_t)(l0 + l) * 576 + 528 + n];
  }
  float A[16];
  #pragma unroll
  for (int n = 0; n < 16; n += 4) {
    float4 v = *(const float4*)&alog[(size_t)e * 16 + n];
    A[n] = -__expf(v.x); A[n+1] = -__expf(v.y); A[n+2] = -__expf(v.z); A[n+3] = -__expf(v.w);
  }
  float D = dp[e];
  float h[16];
  {
    size_t idx = ((size_t)(dir * CH + chunk) * 8192) + (size_t)e * 16;
    #pragma unroll
    for (int n = 0; n < 16; n += 4) {
      float4 v = *(const float4*)&CIN[idx + n];
      h[n] = v.x; h[n+1] = v.y; h[n+2] = v.z; h[n+3] = v.w;
    }
  }
  __syncthreads();
  #pragma unroll
  for (int t = 0; t < CL; t += 8) {
    float d[8], u[8];
    #pragma unroll
    for (int j = 0; j < 8; ++j) {
      d[j] = prd[(size_t)(l0 + t + j) * 576 + e];
      u[j] = ucp[(size_t)(l0 + t + j) * E_ + e];
    }
    #pragma unroll
    for (int j = 0; j < 8; ++j) {
      float du = d[j] * u[j];
      float y0 = 0.f, y1 = 0.f, y2 = 0.f, y3 = 0.f;
      #pragma unroll
      for (int n = 0; n < 16; n += 4) {
        h[n]   = fmaf(__expf(d[j] * A[n]),   h[n],   du * B_s[t + j][n]);
        h[n+1] = fmaf(__expf(d[j] * A[n+1]), h[n+1], du * B_s[t + j][n+1]);
        h[n+2] = fmaf(__expf(d[j] * A[n+2]), h[n+2], du * B_s[t + j][n+2]);
        h[n+3] = fmaf(__expf(d[j] * A[n+3]), h[n+3], du * B_s[t + j][n+3]);
        y0 = fmaf(h[n],   C_s[t + j][n],   y0);
        y1 = fmaf(h[n+1], C_s[t + j][n+1], y1);
        y2 = fmaf(h[n+2], C_s[t + j][n+2], y2);
        y3 = fmaf(h[n+3], C_s[t + j][n+3], y3);
      }
      Y[(size_t)(l0 + t + j) * E_ + e] = (y0 + y1) + (y2 + y3) + u[j] * D;
    }
  }
}

// ---------------- combine fwd+bwd, gate by silu(z) ----------------
__global__ void combine_k(const float* __restrict__ Y2, const float* __restrict__ XZ,
                          float* __restrict__ YG) {
  int idx = blockIdx.x * 256 + threadIdx.x;
  if (idx >= L_ * E_) return;
  int e = idx & (E_ - 1);
  int l = idx >> 9;
  float y = Y2[idx] + Y2[L_ * E_ + (size_t)(L_ - 1 - l) * E_ + e];
  float z = XZ[(size_t)l * 1024 + 512 + e];
  YG[idx] = y * siluf(z);
}

// ---------------- cross-attention core ----------------
__global__ __launch_bounds__(256) void attn_k(
    const float* __restrict__ Q, const float* __restrict__ te,
    const float* __restrict__ kw, const float* __restrict__ vw, const float* __restrict__ vb,
    float* __restrict__ AO) {
  int lane = threadIdx.x & 63, h = threadIdx.x >> 6;
  int l0 = blockIdx.x * 8;
  const float* kp0 = kw + (size_t)lane * DM_ + h * 64;
  const float* vp0 = vw + h * 64 + lane;
  float vbv = vb[h * 64 + lane];
  for (int p = 0; p < 8; ++p) {
    int l = l0 + p;
    float q = Q[(size_t)l * DM_ + h * 64 + lane];
    float g = 0.f;
    #pragma unroll
    for (int d0 = 0; d0 < 64; d0 += 4) {
      float4 r = *(const float4*)(kp0 + d0);
      g = fmaf(r.x, __shfl(q, d0 + 0), g);
      g = fmaf(r.y, __shfl(q, d0 + 1), g);
      g = fmaf(r.z, __shfl(q, d0 + 2), g);
      g = fmaf(r.w, __shfl(q, d0 + 3), g);
    }
    float tfv[8], pv[8];
    #pragma unroll
    for (int t = 0; t < 8; ++t) {
      tfv[t] = te[(size_t)t * L_ * 64 + (size_t)l * 64 + lane];
      pv[t] = tfv[t] * g;
    }
    #pragma unroll
    for (int t = 0; t < 8; ++t) {
      #pragma unroll
      for (int off = 1; off < 64; off <<= 1) pv[t] += __shfl_xor(pv[t], off);
    }
    float mx = pv[0];
    #pragma unroll
    for (int t = 1; t < 8; ++t) mx = fmaxf(mx, pv[t]);
    float s = 0.f;
    #pragma unroll
    for (int t = 0; t < 8; ++t) { pv[t] = __expf((pv[t] - mx) * 0.125f); s += pv[t]; }
    float inv = 1.f / s;
    float m = 0.f;
    #pragma unroll
    for (int t = 0; t < 8; ++t) m = fmaf(pv[t] * inv, tfv[t], m);
    float o = vbv;
    #pragma unroll 8
    for (int c = 0; c < 64; ++c)
      o = fmaf(__shfl(m, c), vp0[(size_t)c * DM_], o);
    AO[(size_t)l * DM_ + h * 64 + lane] = o;
  }
}

extern "C" void kernel_launch(void* const* d_in, const int* in_sizes, int n_in,
                              void* d_out, int out_size, void* d_ws, size_t ws_size,
                              hipStream_t stream) {
  (void)in_sizes; (void)n_in; (void)out_size; (void)ws_size;
  const float* x_in = (const float*)d_in[0];
  const float* te   = (const float*)d_in[1];
  const float* mnw  = (const float*)d_in[2];
  const float* ipw  = (const float*)d_in[3];
  const float* cw   = (const float*)d_in[4];
  const float* cb   = (const float*)d_in[5];
  const float* xpw  = (const float*)d_in[6];
  const float* dpw  = (const float*)d_in[7];
  const float* dpb  = (const float*)d_in[8];
  const float* alog = (const float*)d_in[9];
  const float* dprm = (const float*)d_in[10];
  const float* opw  = (const float*)d_in[11];
  const float* cnw  = (const float*)d_in[12];
  const float* qw   = (const float*)d_in[13];
  const float* qb   = (const float*)d_in[14];
  const float* kw   = (const float*)d_in[15];
  // d_in[16] = k_b: constant over tracks -> softmax-invariant, unused
  const float* vw   = (const float*)d_in[17];
  const float* vb   = (const float*)d_in[18];
  const float* ow   = (const float*)d_in[19];
  const float* ob   = (const float*)d_in[20];

  float* ws = (float*)d_ws;
  float* X   = ws + 0;          // 524288
  float* XZ  = ws + 524288;     // 2097152
  float* UC  = ws + 2621440;    // 2097152 (dir0, dir1)
  float* PRD = ws + 4718592;    // 2359296 = 2 x 2048 x 576
  float* Y2  = ws + 7077888;    // 2097152
  float* SP  = ws + 9175040;    // 1048576 = 2 x 64 x 8192
  float* SH  = ws + 10223616;   // 1048576
  unsigned short* ipwT = (unsigned short*)(ws + 11272192);  // 524288 fl
  unsigned short* WXT  = (unsigned short*)(ws + 11796480);  // 589824 fl
  unsigned short* opwT = (unsigned short*)(ws + 12386304);  // 262144 fl
  unsigned short* qwT  = (unsigned short*)(ws + 12648448);  // 65536 fl
  unsigned short* owT  = (unsigned short*)(ws + 12713984);  // 65536 fl
  // end: 12779008 floats = 51.1 MB
  float* Hb = UC + 1048576;  // alias UC dir1 (dead when used)
  float* YG = UC;            // alias UC dir0 (dead after scan3)
  float* Qb = SP;            // alias SP (dead in CA phase)
  float* AO = SH;            // alias SH (dead in CA phase)

  tcast_k<<<dim3(32, 8, 4), 256, 0, stream>>>(ipw, ipwT, 256, 1024);
  tcast_k<<<dim3(8, 16, 4), 256, 0, stream>>>(opw, opwT, 512, 256);
  tcast_k<<<dim3(8, 8, 2), 256, 0, stream>>>(qw, qwT, 256, 256);
  tcast_k<<<dim3(8, 8, 2), 256, 0, stream>>>(ow, owT, 256, 256);
  wdt_k<<<dim3(1152, 4), 256, 0, stream>>>(xpw, dpw, WXT);

  hipMemcpyAsync(X, x_in, (size_t)L_ * DM_ * sizeof(float),
                 hipMemcpyDeviceToDevice, stream);

  for (int i = 0; i < 4; ++i) {
    rmsnorm_k<<<512, 256, 0, stream>>>(X, mnw + i * 256, Hb);
    mgemm_k<0><<<dim3(16, 32, 1), 256, 0, stream>>>(
        Hb, 256, 0, ipwT + (size_t)i * 1024 * 256, nullptr, XZ, 1024, 0, 256);
    conv_k<<<4096, 256, 0, stream>>>(XZ, cw + i * 4 * 512, cb + i * 512, UC);
    mgemm_k<1><<<dim3(9, 32, 2), 256, 0, stream>>>(
        UC, 512, 1048576, WXT + (size_t)i * 576 * 512, dpb + i * 512,
        PRD, 576, 1179648, 512);
    scan1_k<<<2 * CH * 2, 256, 0, stream>>>(PRD, UC, alog + (size_t)i * 512 * 16, SP, SH);
    scan2_k<<<64, 256, 0, stream>>>(SP, SH);
    scan3_k<<<2 * CH * 2, 256, 0, stream>>>(PRD, UC, alog + (size_t)i * 512 * 16,
                                            dprm + i * 512, SP, Y2);
    combine_k<<<4096, 256, 0, stream>>>(Y2, XZ, YG);
    mgemm_k<2><<<dim3(4, 32, 1), 256, 0, stream>>>(
        YG, 512, 0, opwT + (size_t)i * 256 * 512, nullptr, X, 256, 0, 512);

    if (i == 1 || i == 3) {
      int j = (i == 1) ? 0 : 1;
      rmsnorm_k<<<512, 256, 0, stream>>>(X, cnw + j * 256, Hb);
      mgemm_k<3><<<dim3(4, 32, 1), 256, 0, stream>>>(
          Hb, 256, 0, qwT + (size_t)j * 256 * 256, qb + j * 256, Qb, 256, 0, 256);
      attn_k<<<256, 256, 0, stream>>>(Qb, te, kw + (size_t)j * 64 * 256,
                                      vw + (size_t)j * 64 * 256, vb + j * 256, AO);
      mgemm_k<4><<<dim3(4, 32, 1), 256, 0, stream>>>(
          AO, 256, 0, owT + (size_t)j * 256 * 256, ob + j * 256, X, 256, 0, 256);
    }
  }

  hipMemcpyAsync(d_out, X, (size_t)L_ * DM_ * sizeof(float),
                 hipMemcpyDeviceToDevice, stream);
}